// Round 3
// baseline (508.084 us; speedup 1.0000x reference)
//
#include <hip/hip_runtime.h>
#include <hip/hip_bf16.h>

// KeySelect2 round 3:
// - convm: each wave now 32 ocs (2 A-frag sets) x 2 col-tiles -> 18 ds_read_b128
//   per 36 MFMAs per kb (was 36:36). Same DMA/barrier structure as round 2.
// - localw: h-register-blocked rewrite. Block = (b, 8 rows, 16 ch); thread holds
//   acc[4ch][8h]; lk (bf16, BN+ReLU applied) staged once per 16 source rows; each
//   9-wide lk window register-reused across up to 9 output rows. Attention read
//   from a pre-transposed att_t[b][k][pix] (coalesced dword loads, L1-reused).
// - attprep: LDS-tile transpose atten [b,pix,81] -> att_t [b,81,pix] (aliases xt).

#define B_ 4
#define CM_ 128

typedef __attribute__((ext_vector_type(8))) short short8;
typedef __attribute__((ext_vector_type(4))) float floatx4;
typedef __attribute__((address_space(3))) unsigned lds_as;
typedef __attribute__((address_space(1))) const unsigned glb_as;

__device__ inline short f2bf(float f) {
  union { float f; unsigned u; } v; v.f = f;
  unsigned r = v.u + 0x7fff + ((v.u >> 16) & 1);  // RNE
  return (short)(r >> 16);
}
__device__ inline float bf2f(unsigned short u) {
  union { unsigned u; float f; } v; v.u = ((unsigned)u) << 16;
  return v.f;
}

// ---------------- weight prepack: [oc][ic][3][3] -> [kb][tap][oc][32] bf16 ---
__global__ void wprep_kernel(const float* __restrict__ w, short* __restrict__ wpk,
                             int cin) {
  int e = blockIdx.x * 256 + threadIdx.x;
  if (e >= cin * 9 * 128) return;
  int icb = e & 31;
  int oc = (e >> 5) & 127;
  int tap = (e >> 12) % 9;
  int kb = e / (32 * 128 * 9);
  wpk[e] = f2bf(w[((size_t)oc * cin + kb * 32 + icb) * 9 + tap]);
}

// ---------------- x prepack: NCHW fp32 -> [b][kb][row][col][unit^sw][8] bf16 --
template <int KB>
__global__ void xprep_kernel(const float* __restrict__ x, short* __restrict__ xt) {
  int kb = blockIdx.x >> 4, rg = blockIdx.x & 15;
  int b = blockIdx.y;
  int row = rg * 4 + (threadIdx.x >> 6);
  int col = threadIdx.x & 63;
  const float* xs = x + (((size_t)b * (KB * 32) + kb * 32) * 64 + row) * 64 + col;
  short* xd = xt + ((((size_t)b * KB + kb) * 64 + row) * 64 + col) * 32;
  int sw = (col >> 1) & 3;
#pragma unroll
  for (int u = 0; u < 4; u++) {
    short8 pk;
#pragma unroll
    for (int j = 0; j < 8; j++) pk[j] = f2bf(xs[(size_t)(u * 8 + j) * 4096]);
    *(short8*)(xd + (u ^ sw) * 8) = pk;
  }
}

// ---------------- MFMA conv ------------------------------------------------
// grid (128, 2); block 512 (8 waves). wave: ocsub=wv&1 (32 ocs), row ng=(wv>>1)&1,
// col-half ch=wv>>2 (2 tiles of 16). 18 B-reads : 36 MFMAs per kb.
template <int KB>
__global__ __launch_bounds__(512, 2)
void convm_kernel(const short* __restrict__ xt, const short* __restrict__ wpk,
                  float* __restrict__ y) {
  __shared__ __attribute__((aligned(16))) short lx[16896];  // 2 x (4 rows x 66 cols x 32)
  int tid = threadIdx.x;
  int lane = tid & 63;
  int wv = tid >> 6;
  int n16 = lane & 15, quad = lane >> 4;
  int pb = blockIdx.x;
  int b = pb >> 5, h0 = (pb & 31) * 2;
  int oc0 = blockIdx.y * 64 + (wv & 1) * 32;
  int ng = (wv >> 1) & 1;
  int ch = wv >> 2;

  // zero pad columns (j=0, j=65) of every row, both buffers
  if (tid < 256) {
    int reg = tid >> 4, dw = tid & 15;
    int bu = reg >> 3, rr = (reg >> 1) & 3, cl = reg & 1;
    *(int*)(lx + bu * 8448 + rr * 2112 + (cl ? 65 : 0) * 32 + dw * 2) = 0;
  }
  // zero out-of-range boundary rows (never DMA'd)
  if (h0 == 0)
    for (int i = tid; i < 2112; i += 512) {
      int bu = i >= 1056; int o = i - bu * 1056;
      *((int*)lx + bu * 4224 + o) = 0;
    }
  if (h0 == 62)
    for (int i = tid; i < 2112; i += 512) {
      int bu = i >= 1056; int o = i - bu * 1056;
      *((int*)lx + bu * 4224 + 3 * 1056 + o) = 0;
    }

  auto dma = [&](int kb, int buf) {
#pragma unroll
    for (int t = 0; t < 2; t++) {
      int idx = wv * 2 + t;          // 16 chunks of 1KB
      int r = idx >> 2, cc = idx & 3;
      int row = h0 - 1 + r;
      if (row >= 0 && row < 64) {
        const short* src = xt + ((((size_t)b * KB + kb) * 64 + row) * 64 + cc * 16) * 32 + lane * 8;
        short* dst = lx + buf * 8448 + r * 2112 + (1 + cc * 16) * 32 + lane * 8;
        __builtin_amdgcn_global_load_lds((glb_as*)src, (lds_as*)dst, 16, 0, 0);
      }
    }
  };

  const short* wb0 = wpk + (size_t)(oc0 + n16) * 32 + quad * 8;
  const short* wb1 = wb0 + 512;  // +16 ocs
  short8 afr[2][9], afn[2][9];
  dma(0, 0);
#pragma unroll
  for (int t = 0; t < 9; t++) {
    afr[0][t] = *(const short8*)(wb0 + t * 4096);
    afr[1][t] = *(const short8*)(wb1 + t * 4096);
  }

  floatx4 acc[2][2];
#pragma unroll
  for (int i = 0; i < 2; i++)
#pragma unroll
    for (int t2 = 0; t2 < 2; t2++) acc[i][t2] = (floatx4){0.f, 0.f, 0.f, 0.f};

  for (int kb = 0; kb < KB; kb++) {
    __syncthreads();
    if (kb + 1 < KB) {
      dma(kb + 1, (kb + 1) & 1);
      const short* wn0 = wb0 + (size_t)(kb + 1) * 36864;
      const short* wn1 = wb1 + (size_t)(kb + 1) * 36864;
#pragma unroll
      for (int t = 0; t < 9; t++) {
        afn[0][t] = *(const short8*)(wn0 + t * 4096);
        afn[1][t] = *(const short8*)(wn1 + t * 4096);
      }
    }
    const short* lb = lx + (kb & 1) * 8448;
#pragma unroll
    for (int tap = 0; tap < 9; tap++) {
      int r = tap / 3, s = tap % 3;
      const short* lr = lb + (ng + r) * 2112;
#pragma unroll
      for (int t2 = 0; t2 < 2; t2++) {
        int c = (ch * 2 + t2) * 16 + n16 + s - 1;  // source col, -1..64
        int uu = quad ^ ((c >> 1) & 3);
        short8 bf = *(const short8*)(lr + (c + 1) * 32 + uu * 8);
        acc[0][t2] = __builtin_amdgcn_mfma_f32_16x16x32_bf16(afr[0][tap], bf, acc[0][t2], 0, 0, 0);
        acc[1][t2] = __builtin_amdgcn_mfma_f32_16x16x32_bf16(afr[1][tap], bf, acc[1][t2], 0, 0, 0);
      }
    }
    if (kb + 1 < KB) {
#pragma unroll
      for (int t = 0; t < 9; t++) { afr[0][t] = afn[0][t]; afr[1][t] = afn[1][t]; }
    }
  }

  int row = h0 + ng, col = n16;
#pragma unroll
  for (int i = 0; i < 2; i++)
#pragma unroll
    for (int t2 = 0; t2 < 2; t2++)
#pragma unroll
      for (int rg = 0; rg < 4; rg++) {
        int oc = oc0 + i * 16 + quad * 4 + rg;
        y[(((size_t)b * CM_ + oc) * 64 + row) * 64 + (ch * 2 + t2) * 16 + col] = acc[i][t2][rg];
      }
}

// ---------------- BN stats -------------------------------------------------
__global__ void bnstats_kernel(const float* __restrict__ y, const float* __restrict__ g,
                               const float* __restrict__ bt, float2* __restrict__ scsh) {
  int c = blockIdx.x;
  int tid = threadIdx.x;
  float s = 0.f, s2 = 0.f;
  for (int b = 0; b < B_; b++) {
    const float4* p = (const float4*)(y + ((size_t)(b * CM_) + c) * 4096);
    for (int i = tid; i < 1024; i += 256) {
      float4 v = p[i];
      s += v.x + v.y + v.z + v.w;
      s2 += v.x * v.x + v.y * v.y + v.z * v.z + v.w * v.w;
    }
  }
  for (int off = 32; off > 0; off >>= 1) {
    s += __shfl_down(s, off);
    s2 += __shfl_down(s2, off);
  }
  __shared__ float rs[4], rq[4];
  if ((tid & 63) == 0) { rs[tid >> 6] = s; rq[tid >> 6] = s2; }
  __syncthreads();
  if (tid == 0) {
    float S = rs[0] + rs[1] + rs[2] + rs[3];
    float Q = rq[0] + rq[1] + rq[2] + rq[3];
    float mean = S * (1.f / 16384.f);
    float var = Q * (1.f / 16384.f) - mean * mean;
    float sc = g[c] * rsqrtf(var + 1e-5f);
    scsh[c] = make_float2(sc, bt[c] - mean * sc);
  }
}

// ---------------- atten transpose: [b,pix,81] -> att_t [b,81,pix] ----------
__global__ void attprep_kernel(const float* __restrict__ atten, float* __restrict__ att_t) {
  __shared__ float tile[5184];
  int b = blockIdx.x >> 6;
  int p0 = (blockIdx.x & 63) * 64;
  const float* src = atten + ((size_t)b * 4096 + p0) * 81;
  for (int e = threadIdx.x; e < 5184; e += 256) tile[e] = src[e];
  __syncthreads();
  for (int f = threadIdx.x; f < 5184; f += 256) {
    int k = f >> 6, w_ = f & 63;
    att_t[((size_t)b * 81 + k) * 4096 + p0 + w_] = tile[w_ * 81 + k];
  }
}

// ---------------- local weighting + subtract -> xt5 (bf16, conv5 layout) ----
// grid (32: b*8+hg, 8: cgroup); block 256 (4 waves). Thread: lane=w, wave=4 ch,
// acc[4][8]. Loop 16 source rows; 9-wide bf16 lk window reused across <=9 h.
__global__ __launch_bounds__(256)
void localw_kernel(const float* __restrict__ y1, const float2* __restrict__ scsh1,
                   const float* __restrict__ y4, const float2* __restrict__ scsh4,
                   const float* __restrict__ att_t, short* __restrict__ xt5) {
  __shared__ unsigned short lkb[16][16][72];  // [ch][srcrow][col+4], bf16, 36.9 KB
  int bx = blockIdx.x;
  int b = bx >> 3, h0 = (bx & 7) * 8;
  int cg = blockIdx.y;
  int tid = threadIdx.x;
  int lane = tid & 63;
  int wv = tid >> 6;

  // stage lk = relu(bn1(y1)) for 16 channels x source rows h0-4..h0+11 (bf16)
  for (int c_l = 0; c_l < 16; c_l++) {
    float2 ss = scsh1[cg * 16 + c_l];
    const float* yp = y1 + ((size_t)(b * CM_) + cg * 16 + c_l) * 4096;
    for (int e = tid; e < 16 * 72; e += 256) {
      int gri = e / 72, j = e % 72;
      int row = h0 - 4 + gri, col = j - 4;
      float v = 0.f;
      if (row >= 0 && row < 64 && col >= 0 && col < 64)
        v = fmaxf(0.f, yp[row * 64 + col] * ss.x + ss.y);
      lkb[c_l][gri][j] = (unsigned short)f2bf(v);
    }
  }
  __syncthreads();

  float acc[4][8];
#pragma unroll
  for (int cc = 0; cc < 4; cc++)
#pragma unroll
    for (int h_i = 0; h_i < 8; h_i++) acc[cc][h_i] = 0.f;

  const float* ab = att_t + (size_t)b * 81 * 4096 + h0 * 64 + lane;

  for (int gri = 0; gri < 16; ++gri) {
    float win[4][9];
#pragma unroll
    for (int cc = 0; cc < 4; ++cc)
#pragma unroll
      for (int dw = 0; dw < 9; ++dw)
        win[cc][dw] = bf2f(lkb[wv * 4 + cc][gri][lane + dw]);
#pragma unroll
    for (int h_i = 0; h_i < 8; ++h_i) {
      int r = gri - h_i;
      if (r < 0 || r > 8) continue;  // uniform per block
      const float* ap = ab + (size_t)(r * 9) * 4096 + h_i * 64;
      float a[9];
#pragma unroll
      for (int dw = 0; dw < 9; ++dw) a[dw] = ap[(size_t)dw * 4096];
#pragma unroll
      for (int cc = 0; cc < 4; ++cc)
#pragma unroll
        for (int dw = 0; dw < 9; ++dw)
          acc[cc][h_i] = fmaf(a[dw], win[cc][dw], acc[cc][h_i]);
    }
  }

  // epilogue: subtract relu(bn4(y4)), emit bf16 in conv5 xt layout
#pragma unroll
  for (int cc = 0; cc < 4; ++cc) {
    int c = cg * 16 + wv * 4 + cc;
    float2 ss4 = scsh4[c];
    int icb = c & 31;
    int uu = (icb >> 3) ^ ((lane >> 1) & 3);
#pragma unroll
    for (int h_i = 0; h_i < 8; ++h_i) {
      int h = h0 + h_i;
      size_t gi = ((size_t)(b * CM_) + c) * 4096 + h * 64 + lane;
      float lnk = fmaxf(0.f, y4[gi] * ss4.x + ss4.y);
      float dv = acc[cc][h_i] - lnk;
      xt5[((((size_t)b * 4 + (c >> 5)) * 64 + h) * 64 + lane) * 32 + uu * 8 + (icb & 7)] =
          f2bf(dv);
    }
  }
}

// ---------------- global avg pool with BN+ReLU ----------------------------
__global__ void pool_kernel(const float* __restrict__ y, const float2* __restrict__ scsh,
                            float* __restrict__ pooled) {
  int bc = blockIdx.x;
  int c = bc & 127;
  float2 ss = scsh[c];
  const float4* p = (const float4*)(y + (size_t)bc * 4096);
  float s = 0.f;
  for (int i = threadIdx.x; i < 1024; i += 256) {
    float4 v = p[i];
    s += fmaxf(0.f, v.x * ss.x + ss.y) + fmaxf(0.f, v.y * ss.x + ss.y) +
         fmaxf(0.f, v.z * ss.x + ss.y) + fmaxf(0.f, v.w * ss.x + ss.y);
  }
  for (int off = 32; off > 0; off >>= 1) s += __shfl_down(s, off);
  __shared__ float rs[4];
  if ((threadIdx.x & 63) == 0) rs[threadIdx.x >> 6] = s;
  __syncthreads();
  if (threadIdx.x == 0) pooled[bc] = (rs[0] + rs[1] + rs[2] + rs[3]) * (1.f / 4096.f);
}

// ---------------- fc1 + fc2 -----------------------------------------------
__global__ void fc_kernel(const float* __restrict__ pooled, const float* __restrict__ fc1w,
                          const float* __restrict__ fc1b, const float* __restrict__ fc2w,
                          const float* __restrict__ fc2b, float* __restrict__ out) {
  int lane = threadIdx.x;
  float p[B_][10];
#pragma unroll
  for (int b = 0; b < B_; b++)
#pragma unroll
    for (int j = 0; j < 10; j++) p[b][j] = 0.f;
  for (int c = lane; c < CM_; c += 64) {
#pragma unroll
    for (int b = 0; b < B_; b++) {
      float pv = pooled[b * CM_ + c];
#pragma unroll
      for (int j = 0; j < 10; j++) p[b][j] = fmaf(pv, fc1w[j * CM_ + c], p[b][j]);
    }
  }
  for (int off = 32; off > 0; off >>= 1)
#pragma unroll
    for (int b = 0; b < B_; b++)
#pragma unroll
      for (int j = 0; j < 10; j++) p[b][j] += __shfl_down(p[b][j], off);
  if (lane == 0) {
    for (int b = 0; b < B_; b++) {
      float o = fc2b[0];
      for (int j = 0; j < 10; j++) o += fc2w[j] * (p[b][j] + fc1b[j]);
      out[b] = o;
    }
  }
}

extern "C" void kernel_launch(void* const* d_in, const int* in_sizes, int n_in,
                              void* d_out, int out_size, void* d_ws, size_t ws_size,
                              hipStream_t stream) {
  const float* low_key    = (const float*)d_in[0];
  const float* low_nonkey = (const float*)d_in[1];
  const float* atten      = (const float*)d_in[2];
  const float* w1  = (const float*)d_in[3];
  const float* g1  = (const float*)d_in[4];
  const float* b1  = (const float*)d_in[5];
  const float* w4  = (const float*)d_in[6];
  const float* g4  = (const float*)d_in[7];
  const float* b4  = (const float*)d_in[8];
  const float* w5  = (const float*)d_in[9];
  const float* g5  = (const float*)d_in[10];
  const float* b5  = (const float*)d_in[11];
  const float* fc1w = (const float*)d_in[12];
  const float* fc1b = (const float*)d_in[13];
  const float* fc2w = (const float*)d_in[14];
  const float* fc2b = (const float*)d_in[15];

  char* w8 = (char*)d_ws;
  short* wpk = (short*)w8;                                   // 2,359,296 B (max)
  short* xt  = (short*)(w8 + 2359296);                       // 33,554,432 B
  short* xt5 = (short*)(w8 + 2359296 + 33554432);            // 4,194,304 B
  float* y1  = (float*)(w8 + 2359296 + 33554432 + 4194304);  // 8,388,608 B
  float* y4  = y1 + 2097152;                                 // 8,388,608 B
  float2* scsh1 = (float2*)(y4 + 2097152);
  float2* scsh4 = scsh1 + CM_;
  float2* scsh5 = scsh4 + CM_;
  float* pooled = (float*)(scsh5 + CM_);
  float* att_t = (float*)xt;  // aliases xt: xt dead after conv4's convm
  float* out = (float*)d_out;

  // conv1 path
  wprep_kernel<<<4608, 256, 0, stream>>>(w1, wpk, 1024);
  xprep_kernel<32><<<dim3(512, 4), 256, 0, stream>>>(low_key, xt);
  convm_kernel<32><<<dim3(128, 2), 512, 0, stream>>>(xt, wpk, y1);
  bnstats_kernel<<<128, 256, 0, stream>>>(y1, g1, b1, scsh1);

  // conv4 path (reuses wpk/xt — stream-ordered)
  wprep_kernel<<<4608, 256, 0, stream>>>(w4, wpk, 1024);
  xprep_kernel<32><<<dim3(512, 4), 256, 0, stream>>>(low_nonkey, xt);
  convm_kernel<32><<<dim3(128, 2), 512, 0, stream>>>(xt, wpk, y4);
  bnstats_kernel<<<128, 256, 0, stream>>>(y4, g4, b4, scsh4);

  // attention transpose (att_t aliases xt, which is now dead)
  attprep_kernel<<<256, 256, 0, stream>>>(atten, att_t);

  // local weighting + subtract, emits conv5 input in xt layout
  localw_kernel<<<dim3(32, 8), 256, 0, stream>>>(y1, scsh1, y4, scsh4, att_t, xt5);

  // conv5 path (output into y1 buffer)
  wprep_kernel<<<576, 256, 0, stream>>>(w5, wpk, 128);
  convm_kernel<4><<<dim3(128, 2), 512, 0, stream>>>(xt5, wpk, y1);
  bnstats_kernel<<<128, 256, 0, stream>>>(y1, g5, b5, scsh5);

  pool_kernel<<<512, 256, 0, stream>>>(y1, scsh5, pooled);
  fc_kernel<<<1, 64, 0, stream>>>(pooled, fc1w, fc1b, fc2w, fc2b, out);
}